// Round 1
// baseline (2698.159 us; speedup 1.0000x reference)
//
#include <hip/hip_runtime.h>
#include <math.h>

#define HD 1024
#define BB 256
#define NCAM 15
#define TT 60
#define G3 3072
#define LDW 36      // f32 LDS stride for gi kernel
#define NS 24       // samples per pass, gi kernel
#define TCH 20      // ring chunk (timesteps) for coalesced out staging

typedef short bf16x8 __attribute__((ext_vector_type(8)));
typedef float f32x4 __attribute__((ext_vector_type(4)));

__device__ __forceinline__ unsigned short f2bf(float f) {
    unsigned int u = __float_as_uint(f);
    u += 0x7fffu + ((u >> 16) & 1u);       // RNE
    return (unsigned short)(u >> 16);
}
__device__ __forceinline__ float bf2f(unsigned short h) {
    return __uint_as_float(((unsigned int)h) << 16);
}
__device__ __forceinline__ float sigf(float v) { return 1.f / (1.f + expf(-v)); }

// async global->LDS, 16B per lane; LDS dest = wave-uniform base + lane*16
__device__ __forceinline__ void dma16(const void* g, void* l) {
    __builtin_amdgcn_global_load_lds(
        (const __attribute__((address_space(1))) unsigned int*)g,
        (__attribute__((address_space(3))) unsigned int*)l, 16, 0, 0);
}

// ---------------- grouping ----------------
__global__ void group_kernel(const int* __restrict__ cam,
                             int* __restrict__ off, int* __restrict__ list) {
    __shared__ int cnt[NCAM];
    __shared__ int soff[NCAM + 1];
    int tid = threadIdx.x;
    if (tid < NCAM) cnt[tid] = 0;
    __syncthreads();
    int c = cam[tid];
    int pos = atomicAdd(&cnt[c], 1);
    __syncthreads();
    if (tid == 0) {
        soff[0] = 0;
        for (int i = 0; i < NCAM; ++i) soff[i + 1] = soff[i] + cnt[i];
    }
    __syncthreads();
    list[soff[c] + pos] = tid;
    if (tid <= NCAM) off[tid] = soff[tid];
}

// ---------------- per-camera input projection (f32, unchanged) ----------------
__global__ __launch_bounds__(256) void gi_gemm_kernel(
    const float* __restrict__ W_ih, const float* __restrict__ b_ih,
    const float* __restrict__ b_hh, const float* __restrict__ x,
    const int* __restrict__ off, const int* __restrict__ list,
    float* __restrict__ gi) {
    int c  = blockIdx.x;
    int r0 = blockIdx.y * 96;
    int tid = threadIdx.x;
    int tx = tid & 7, ty = tid >> 3;

    __shared__ __align__(16) float wlds[96 * LDW];
    __shared__ __align__(16) float hlds[NS * LDW];
    __shared__ int slist[NS];

    int base = off[c];
    int nc = off[c + 1] - base;

    for (int s0 = 0; s0 < nc; s0 += NS) {
        __syncthreads();
        if (tid < NS) slist[tid] = (s0 + tid < nc) ? list[base + s0 + tid] : -1;
        __syncthreads();

        float acc[3][3];
#pragma unroll
        for (int g = 0; g < 3; ++g)
#pragma unroll
            for (int q = 0; q < 3; ++q) acc[g][q] = 0.f;

        for (int k0 = 0; k0 < HD; k0 += 32) {
#pragma unroll
            for (int i = 0; i < 3; ++i) {
                int idx = tid + 256 * i;
                int row = idx >> 3, col4 = idx & 7;
                float4 w = *(const float4*)(W_ih +
                    ((size_t)c * G3 + r0 + row) * HD + k0 + col4 * 4);
                *(float4*)(wlds + row * LDW + col4 * 4) = w;
            }
            {
                int s = tid >> 3, col4 = tid & 7;
                if (s < NS) {
                    int b = slist[s];
                    float4 hv = make_float4(0.f, 0.f, 0.f, 0.f);
                    if (b >= 0)
                        hv = *(const float4*)(x + (size_t)b * HD + k0 + col4 * 4);
                    *(float4*)(hlds + s * LDW + col4 * 4) = hv;
                }
            }
            __syncthreads();
#pragma unroll
            for (int kk = 0; kk < 32; kk += 4) {
                float4 w0 = *(const float4*)(wlds + (0 * 32 + ty) * LDW + kk);
                float4 w1 = *(const float4*)(wlds + (1 * 32 + ty) * LDW + kk);
                float4 w2 = *(const float4*)(wlds + (2 * 32 + ty) * LDW + kk);
#pragma unroll
                for (int q = 0; q < 3; ++q) {
                    float4 hv = *(const float4*)(hlds + (tx + 8 * q) * LDW + kk);
                    acc[0][q] += w0.x * hv.x + w0.y * hv.y + w0.z * hv.z + w0.w * hv.w;
                    acc[1][q] += w1.x * hv.x + w1.y * hv.y + w1.z * hv.z + w1.w * hv.w;
                    acc[2][q] += w2.x * hv.x + w2.y * hv.y + w2.z * hv.z + w2.w * hv.w;
                }
            }
            __syncthreads();
        }
#pragma unroll
        for (int q = 0; q < 3; ++q) {
            int b = slist[tx + 8 * q];
            if (b >= 0) {
#pragma unroll
                for (int g = 0; g < 3; ++g) {
                    int R = r0 + g * 32 + ty;
                    float bias = b_ih[c * G3 + R];
                    if (R < 2 * HD) bias += b_hh[c * G3 + R];
                    gi[(size_t)b * G3 + R] = acc[g][q] + bias;
                }
            }
        }
    }
}

// ---------------- W_hh -> split-bf16 DMA-image prep ----------------
__global__ __launch_bounds__(256) void prep_kernel(
    const float* __restrict__ W_hh, unsigned short* __restrict__ Wimg) {
    int c = blockIdx.z, jt = blockIdx.y;
    int lin = blockIdx.x * 256 + threadIdx.x;   // [0, 12288) = 16 iters * 768 chunks
    int it  = lin / 768;
    int rem = lin - it * 768;
    int r = rem >> 3, kcp = rem & 7;
    int gate = r >> 5, jl = r & 31;
    int kc = kcp ^ (r & 7);
    int k = it * 64 + kc * 8;
    const float* src = W_hh + ((size_t)c * G3 + gate * HD + jt * 32 + jl) * HD + k;
    float4 v0 = *(const float4*)src;
    float4 v1 = *(const float4*)(src + 4);
    float v[8] = {v0.x, v0.y, v0.z, v0.w, v1.x, v1.y, v1.z, v1.w};
    unsigned int hp[4], lp[4];
#pragma unroll
    for (int e = 0; e < 4; ++e) {
        unsigned short h0 = f2bf(v[2 * e]), h1 = f2bf(v[2 * e + 1]);
        unsigned short g0 = f2bf(v[2 * e] - bf2f(h0));
        unsigned short g1 = f2bf(v[2 * e + 1] - bf2f(h1));
        hp[e] = (unsigned)h0 | ((unsigned)h1 << 16);
        lp[e] = (unsigned)g0 | ((unsigned)g1 << 16);
    }
    unsigned short* dhi = Wimg + ((size_t)(c * 32 + jt) * 16 + it) * 12288 + r * 64 + kcp * 8;
    *(uint4*)dhi = make_uint4(hp[0], hp[1], hp[2], hp[3]);
    *(uint4*)(dhi + 6144) = make_uint4(lp[0], lp[1], lp[2], lp[3]);
}

// ---------------- fused recurrent step: 2-phase DMA pipeline + MFMA ----------------
// h_out is a coalesced f32 ring plane [B][H] (doubles as next step's h_in);
// out is staged via the ring + tr_kernel (no scattered dword stores here).
__global__ __launch_bounds__(128) void step_dma_kernel(
    const unsigned short* __restrict__ Wimg, const float* __restrict__ b_hh,
    const float* __restrict__ gi, const int* __restrict__ off,
    const int* __restrict__ list, const float* __restrict__ h_in,
    const unsigned short* __restrict__ hhi_in, const unsigned short* __restrict__ hlo_in,
    const unsigned short* __restrict__ hzero,
    float* __restrict__ h_out, unsigned short* __restrict__ hhi_out,
    unsigned short* __restrict__ hlo_out) {
    int c  = blockIdx.x;
    int jt = blockIdx.y;
    int j0 = jt * 32;
    int tid = threadIdx.x;
    int lane = tid & 63;
    int w = tid >> 6;
    int l15 = lane & 15;
    int l4  = lane >> 4;

    __shared__ __align__(16) unsigned short Ash[2][12288];  // dbuf x (2 planes x 96 x 64)
    __shared__ __align__(16) unsigned short Bsh[2][4096];   // dbuf x (2 planes x 32 x 64)
    __shared__ int slist[32];

    const unsigned short* wbase = Wimg + (size_t)(c * 32 + jt) * 16 * 12288;
    int base = off[c];
    int nc = off[c + 1] - base;

    // B DMA decode (4 insts x 128 threads = 512 chunks = 2 planes x 32 s x 8 kc')
    int bs[4], bkc[4], bpl[4];
#pragma unroll
    for (int i = 0; i < 4; ++i) {
        int p = i * 128 + tid;
        bpl[i] = p >> 8;
        bs[i]  = (p >> 3) & 31;
        bkc[i] = (p & 7) ^ (bs[i] & 7);   // global k-chunk after inverse swizzle
    }

    for (int s0 = 0; s0 < nc; s0 += 32) {
        __syncthreads();
        if (tid < 32) slist[tid] = (s0 + tid < nc) ? list[base + s0 + tid] : -1;
        __syncthreads();
        int rem = nc - s0;
        int nq = (rem > 16) ? 2 : 1;

        const unsigned short* bg[4];
        int bstep[4];
#pragma unroll
        for (int i = 0; i < 4; ++i) {
            int b = slist[bs[i]];
            const unsigned short* hp = bpl[i] ? hlo_in : hhi_in;
            bg[i] = (b >= 0) ? hp + (size_t)b * HD + bkc[i] * 8 : hzero;
            bstep[i] = (b >= 0) ? 1 : 0;
        }

        f32x4 acc[3][2];
#pragma unroll
        for (int g = 0; g < 3; ++g)
#pragma unroll
            for (int q = 0; q < 2; ++q) acc[g][q] = (f32x4){0.f, 0.f, 0.f, 0.f};

#define STAGE(NB, IT) do {                                                        \
        const char* asrc_ = (const char*)(wbase + (size_t)(IT) * 12288);          \
        _Pragma("unroll")                                                         \
        for (int i_ = 0; i_ < 12; ++i_)                                           \
            dma16(asrc_ + (i_ * 128 + tid) * 16,                                  \
                  (char*)(Ash[NB]) + (i_ * 128 + (w << 6)) * 16);                 \
        int k0_ = (IT) * 64;                                                      \
        _Pragma("unroll")                                                         \
        for (int i_ = 0; i_ < 4; ++i_)                                            \
            dma16(bg[i_] + k0_ * bstep[i_],                                       \
                  (char*)(Bsh[NB]) + (i_ * 128 + (w << 6)) * 16);                 \
    } while (0)

        // pipeline prologue: tile 0 into buffer 0, drain, barrier
        STAGE(0, 0);
        asm volatile("s_waitcnt vmcnt(0)" ::: "memory");
        __builtin_amdgcn_s_barrier();

#pragma unroll 2
        for (int it = 0; it < 16; ++it) {
            int cur = it & 1;
            if (it < 15) STAGE(cur ^ 1, it + 1);   // next tile in flight during compute

            const unsigned short* Acur = Ash[cur];
            const unsigned short* Bcur = Bsh[cur];
#pragma unroll
            for (int kt = 0; kt < 2; ++kt) {
                int kc = kt * 4 + l4;
                bf16x8 bh[2], bl[2];
#pragma unroll
                for (int q = 0; q < 2; ++q) {
                    if (q < nq) {
                        int s = q * 16 + l15;
                        int boff = s * 64 + ((kc ^ (s & 7)) * 8);
                        bh[q] = *(const bf16x8*)(&Bcur[boff]);
                        bl[q] = *(const bf16x8*)(&Bcur[2048 + boff]);
                    }
                }
#pragma unroll
                for (int g = 0; g < 3; ++g) {
                    int r = g * 32 + w * 16 + l15;
                    int aoff = r * 64 + ((kc ^ (r & 7)) * 8);
                    bf16x8 ah = *(const bf16x8*)(&Acur[aoff]);
                    bf16x8 al = *(const bf16x8*)(&Acur[6144 + aoff]);
#pragma unroll
                    for (int q = 0; q < 2; ++q) {
                        if (q < nq) {
                            acc[g][q] = __builtin_amdgcn_mfma_f32_16x16x32_bf16(ah, bh[q], acc[g][q], 0, 0, 0);
                            acc[g][q] = __builtin_amdgcn_mfma_f32_16x16x32_bf16(al, bh[q], acc[g][q], 0, 0, 0);
                            acc[g][q] = __builtin_amdgcn_mfma_f32_16x16x32_bf16(ah, bl[q], acc[g][q], 0, 0, 0);
                        }
                    }
                }
            }
            if (it < 15) {
                asm volatile("s_waitcnt vmcnt(0)" ::: "memory");  // next tile landed
                __builtin_amdgcn_s_barrier();                     // all waves past reads of it-1 buf
            }
        }
#undef STAGE

        // ---- GRU epilogue (coalesced stores only) ----
        int j = j0 + w * 16 + l4 * 4;
        f32x4 bhn = *(const f32x4*)(b_hh + c * G3 + 2 * HD + j);
#pragma unroll
        for (int q = 0; q < 2; ++q) {
            if (q < nq) {
                int b = slist[q * 16 + l15];
                if (b >= 0) {
                    const float* gib = gi + (size_t)b * G3;
                    f32x4 gr = *(const f32x4*)(gib + j);
                    f32x4 gz = *(const f32x4*)(gib + HD + j);
                    f32x4 gn = *(const f32x4*)(gib + 2 * HD + j);
                    f32x4 hp = *(const f32x4*)(h_in + (size_t)b * HD + j);
                    f32x4 hn;
                    unsigned int hiw[2], low[2];
#pragma unroll
                    for (int e = 0; e < 4; ++e) {
                        float r = sigf(gr[e] + acc[0][q][e]);
                        float z = sigf(gz[e] + acc[1][q][e]);
                        float n = tanhf(gn[e] + r * (acc[2][q][e] + bhn[e]));
                        hn[e] = (1.f - z) * n + z * hp[e];
                    }
#pragma unroll
                    for (int e = 0; e < 2; ++e) {
                        unsigned short h0 = f2bf(hn[2 * e]), h1 = f2bf(hn[2 * e + 1]);
                        unsigned short g0 = f2bf(hn[2 * e] - bf2f(h0));
                        unsigned short g1 = f2bf(hn[2 * e + 1] - bf2f(h1));
                        hiw[e] = (unsigned)h0 | ((unsigned)h1 << 16);
                        low[e] = (unsigned)g0 | ((unsigned)g1 << 16);
                    }
                    *(f32x4*)(h_out + (size_t)b * HD + j) = hn;
                    *(uint2*)(hhi_out + (size_t)b * HD + j) = make_uint2(hiw[0], hiw[1]);
                    *(uint2*)(hlo_out + (size_t)b * HD + j) = make_uint2(low[0], low[1]);
                }
            }
        }
    }
}

// ---------------- ring [TCH][B][H] -> out [B][H][T] chunk transpose ----------------
__global__ __launch_bounds__(256) void tr_kernel(
    const float* __restrict__ ring, float* __restrict__ out, int t0) {
    int r = blockIdx.x * 256 + threadIdx.x;   // row in [0, B*H)
    float v[TCH];
#pragma unroll
    for (int tt = 0; tt < TCH; ++tt)
        v[tt] = ring[(size_t)tt * (BB * HD) + r];   // coalesced plane reads
    float* dst = out + (size_t)r * TT + t0;         // 80B contiguous per row
#pragma unroll
    for (int e = 0; e < TCH / 4; ++e)
        *(f32x4*)(dst + 4 * e) = (f32x4){v[4 * e], v[4 * e + 1], v[4 * e + 2], v[4 * e + 3]};
}

extern "C" void kernel_launch(void* const* d_in, const int* in_sizes, int n_in,
                              void* d_out, int out_size, void* d_ws, size_t ws_size,
                              hipStream_t stream) {
    const float* x    = (const float*)d_in[0];
    const int*   cam  = (const int*)d_in[1];
    const float* W_ih = (const float*)d_in[2];
    const float* W_hh = (const float*)d_in[3];
    const float* b_ih = (const float*)d_in[4];
    const float* b_hh = (const float*)d_in[5];
    float* out = (float*)d_out;

    char* ws = (char*)d_ws;
    int*   off   = (int*)ws;                               // 64 B
    int*   list  = (int*)(ws + 64);                        // 1 KB
    unsigned short* hzero = (unsigned short*)(ws + 2048);  // 2 KB zeros
    float* gi    = (float*)(ws + 4096);                    // 3 MB
    float* hZ    = (float*)(ws + 3149824);                 // 1 MB zero f32 plane (t=0 h_in)
    unsigned short* hhiA = (unsigned short*)(ws + 4198400);  // 512 KB
    unsigned short* hloA = (unsigned short*)(ws + 4722688);  // 512 KB
    unsigned short* hhiB = (unsigned short*)(ws + 5246976);  // 512 KB
    unsigned short* hloB = (unsigned short*)(ws + 5771264);  // 512 KB
    float* ring  = (float*)(ws + 6295552);                 // 20 MB: TCH x B x H f32
    unsigned short* Wimg = (unsigned short*)(ws + 27267072); // 188.7 MB

    group_kernel<<<1, 256, 0, stream>>>(cam, off, list);
    gi_gemm_kernel<<<dim3(NCAM, G3 / 96), 256, 0, stream>>>(
        W_ih, b_ih, b_hh, x, off, list, gi);
    prep_kernel<<<dim3(48, 32, NCAM), 256, 0, stream>>>(W_hh, Wimg);
    hipMemsetAsync(hzero, 0, 2048, stream);
    hipMemsetAsync(hZ, 0, (size_t)BB * HD * sizeof(float), stream);
    hipMemsetAsync(hhiA, 0, (size_t)BB * HD * 2 * sizeof(short), stream); // hhiA+hloA

    const float* hin = hZ;
    const unsigned short* hhi_in = hhiA;  unsigned short* hhi_out = hhiB;
    const unsigned short* hlo_in = hloA;  unsigned short* hlo_out = hloB;
    for (int t = 0; t < TT; ++t) {
        float* ringplane = ring + (size_t)(t % TCH) * BB * HD;
        step_dma_kernel<<<dim3(NCAM, HD / 32), 128, 0, stream>>>(
            Wimg, b_hh, gi, off, list, hin, hhi_in, hlo_in, hzero,
            ringplane, hhi_out, hlo_out);
        hin = ringplane;
        { const unsigned short* tmp = hhi_in; hhi_in = hhi_out; hhi_out = (unsigned short*)tmp; }
        { const unsigned short* tmp = hlo_in; hlo_in = hlo_out; hlo_out = (unsigned short*)tmp; }
        if ((t % TCH) == TCH - 1)
            tr_kernel<<<BB * HD / 256, 256, 0, stream>>>(ring, out, t - (TCH - 1));
    }
}

// Round 2
// 1817.248 us; speedup vs baseline: 1.4847x; 1.4847x over previous
//
#include <hip/hip_runtime.h>
#include <math.h>

#define HD 1024
#define BB 256
#define NCAM 15
#define TT 60
#define G3 3072
#define LDW 36      // f32 LDS stride for gi kernel
#define NS 24       // samples per pass, gi kernel
#define TCH 20      // ring chunk (timesteps) for coalesced out staging

typedef short bf16x8 __attribute__((ext_vector_type(8)));
typedef _Float16 f16x8 __attribute__((ext_vector_type(8)));
typedef float f32x4 __attribute__((ext_vector_type(4)));

__device__ __forceinline__ unsigned short f2h(float f) {
    _Float16 h = (_Float16)f;             // v_cvt_f16_f32, RNE
    unsigned short u;
    __builtin_memcpy(&u, &h, 2);
    return u;
}
__device__ __forceinline__ float sigf(float v) { return 1.f / (1.f + expf(-v)); }

// async global->LDS, 16B per lane; LDS dest = wave-uniform base + lane*16
__device__ __forceinline__ void dma16(const void* g, void* l) {
    __builtin_amdgcn_global_load_lds(
        (const __attribute__((address_space(1))) unsigned int*)g,
        (__attribute__((address_space(3))) unsigned int*)l, 16, 0, 0);
}

// ---------------- grouping ----------------
__global__ void group_kernel(const int* __restrict__ cam,
                             int* __restrict__ off, int* __restrict__ list) {
    __shared__ int cnt[NCAM];
    __shared__ int soff[NCAM + 1];
    int tid = threadIdx.x;
    if (tid < NCAM) cnt[tid] = 0;
    __syncthreads();
    int c = cam[tid];
    int pos = atomicAdd(&cnt[c], 1);
    __syncthreads();
    if (tid == 0) {
        soff[0] = 0;
        for (int i = 0; i < NCAM; ++i) soff[i + 1] = soff[i] + cnt[i];
    }
    __syncthreads();
    list[soff[c] + pos] = tid;
    if (tid <= NCAM) off[tid] = soff[tid];
}

// ---------------- per-camera input projection (f32, unchanged) ----------------
__global__ __launch_bounds__(256) void gi_gemm_kernel(
    const float* __restrict__ W_ih, const float* __restrict__ b_ih,
    const float* __restrict__ b_hh, const float* __restrict__ x,
    const int* __restrict__ off, const int* __restrict__ list,
    float* __restrict__ gi) {
    int c  = blockIdx.x;
    int r0 = blockIdx.y * 96;
    int tid = threadIdx.x;
    int tx = tid & 7, ty = tid >> 3;

    __shared__ __align__(16) float wlds[96 * LDW];
    __shared__ __align__(16) float hlds[NS * LDW];
    __shared__ int slist[NS];

    int base = off[c];
    int nc = off[c + 1] - base;

    for (int s0 = 0; s0 < nc; s0 += NS) {
        __syncthreads();
        if (tid < NS) slist[tid] = (s0 + tid < nc) ? list[base + s0 + tid] : -1;
        __syncthreads();

        float acc[3][3];
#pragma unroll
        for (int g = 0; g < 3; ++g)
#pragma unroll
            for (int q = 0; q < 3; ++q) acc[g][q] = 0.f;

        for (int k0 = 0; k0 < HD; k0 += 32) {
#pragma unroll
            for (int i = 0; i < 3; ++i) {
                int idx = tid + 256 * i;
                int row = idx >> 3, col4 = idx & 7;
                float4 w = *(const float4*)(W_ih +
                    ((size_t)c * G3 + r0 + row) * HD + k0 + col4 * 4);
                *(float4*)(wlds + row * LDW + col4 * 4) = w;
            }
            {
                int s = tid >> 3, col4 = tid & 7;
                if (s < NS) {
                    int b = slist[s];
                    float4 hv = make_float4(0.f, 0.f, 0.f, 0.f);
                    if (b >= 0)
                        hv = *(const float4*)(x + (size_t)b * HD + k0 + col4 * 4);
                    *(float4*)(hlds + s * LDW + col4 * 4) = hv;
                }
            }
            __syncthreads();
#pragma unroll
            for (int kk = 0; kk < 32; kk += 4) {
                float4 w0 = *(const float4*)(wlds + (0 * 32 + ty) * LDW + kk);
                float4 w1 = *(const float4*)(wlds + (1 * 32 + ty) * LDW + kk);
                float4 w2 = *(const float4*)(wlds + (2 * 32 + ty) * LDW + kk);
#pragma unroll
                for (int q = 0; q < 3; ++q) {
                    float4 hv = *(const float4*)(hlds + (tx + 8 * q) * LDW + kk);
                    acc[0][q] += w0.x * hv.x + w0.y * hv.y + w0.z * hv.z + w0.w * hv.w;
                    acc[1][q] += w1.x * hv.x + w1.y * hv.y + w1.z * hv.z + w1.w * hv.w;
                    acc[2][q] += w2.x * hv.x + w2.y * hv.y + w2.z * hv.z + w2.w * hv.w;
                }
            }
            __syncthreads();
        }
#pragma unroll
        for (int q = 0; q < 3; ++q) {
            int b = slist[tx + 8 * q];
            if (b >= 0) {
#pragma unroll
                for (int g = 0; g < 3; ++g) {
                    int R = r0 + g * 32 + ty;
                    float bias = b_ih[c * G3 + R];
                    if (R < 2 * HD) bias += b_hh[c * G3 + R];
                    gi[(size_t)b * G3 + R] = acc[g][q] + bias;
                }
            }
        }
    }
}

// ---------------- W_hh -> fp16 DMA-image prep (single plane) ----------------
// Image per (cam, jtile, iter): 768 chunks of 16B in the exact order the step
// kernel's DMA deposits. chunk (r, kc') holds global k = it*64 + (kc'^(r&7))*8 .. +8.
__global__ __launch_bounds__(256) void prep_kernel(
    const float* __restrict__ W_hh, unsigned short* __restrict__ Wimg) {
    int c = blockIdx.z, jt = blockIdx.y;
    int lin = blockIdx.x * 256 + threadIdx.x;   // [0, 12288) = 16 iters * 768 chunks
    int it  = lin / 768;
    int rem = lin - it * 768;
    int r = rem >> 3, kcp = rem & 7;
    int gate = r >> 5, jl = r & 31;
    int kc = kcp ^ (r & 7);
    int k = it * 64 + kc * 8;
    const float* src = W_hh + ((size_t)c * G3 + gate * HD + jt * 32 + jl) * HD + k;
    float4 v0 = *(const float4*)src;
    float4 v1 = *(const float4*)(src + 4);
    float v[8] = {v0.x, v0.y, v0.z, v0.w, v1.x, v1.y, v1.z, v1.w};
    unsigned int hp[4];
#pragma unroll
    for (int e = 0; e < 4; ++e) {
        unsigned short h0 = f2h(v[2 * e]), h1 = f2h(v[2 * e + 1]);
        hp[e] = (unsigned)h0 | ((unsigned)h1 << 16);
    }
    unsigned short* dst = Wimg + ((size_t)(c * 32 + jt) * 16 + it) * 6144 + r * 64 + kcp * 8;
    *(uint4*)dst = make_uint4(hp[0], hp[1], hp[2], hp[3]);
}

// ---------------- fused recurrent step: fp16 weights, 2-phase DMA + MFMA ----------------
__global__ __launch_bounds__(128) void step_dma_kernel(
    const unsigned short* __restrict__ Wimg, const float* __restrict__ b_hh,
    const float* __restrict__ gi, const int* __restrict__ off,
    const int* __restrict__ list, const float* __restrict__ h_in,
    const unsigned short* __restrict__ hf_in, const unsigned short* __restrict__ hzero,
    float* __restrict__ h_out, unsigned short* __restrict__ hf_out) {
    int c  = blockIdx.x;
    int jt = blockIdx.y;
    int j0 = jt * 32;
    int tid = threadIdx.x;
    int lane = tid & 63;
    int w = tid >> 6;
    int l15 = lane & 15;
    int l4  = lane >> 4;

    __shared__ __align__(16) unsigned short Ash[2][6144];  // dbuf x (96 x 64 fp16)
    __shared__ __align__(16) unsigned short Bsh[2][2048];  // dbuf x (32 x 64 fp16)
    __shared__ int slist[32];

    const unsigned short* wbase = Wimg + (size_t)(c * 32 + jt) * 16 * 6144;
    int base = off[c];
    int nc = off[c + 1] - base;

    // B DMA decode (2 insts x 128 threads = 256 chunks = 32 s x 8 kc')
    int bs[2], bkc[2];
#pragma unroll
    for (int i = 0; i < 2; ++i) {
        int p = i * 128 + tid;
        bs[i]  = p >> 3;
        bkc[i] = (p & 7) ^ (bs[i] & 7);   // global k-chunk after inverse swizzle
    }

    for (int s0 = 0; s0 < nc; s0 += 32) {
        __syncthreads();
        if (tid < 32) slist[tid] = (s0 + tid < nc) ? list[base + s0 + tid] : -1;
        __syncthreads();
        int rem = nc - s0;
        int nq = (rem > 16) ? 2 : 1;

        const unsigned short* bg[2];
        int bstep[2];
#pragma unroll
        for (int i = 0; i < 2; ++i) {
            int b = slist[bs[i]];
            bg[i] = (b >= 0) ? hf_in + (size_t)b * HD + bkc[i] * 8 : hzero;
            bstep[i] = (b >= 0) ? 1 : 0;
        }

        f32x4 acc[3][2];
#pragma unroll
        for (int g = 0; g < 3; ++g)
#pragma unroll
            for (int q = 0; q < 2; ++q) acc[g][q] = (f32x4){0.f, 0.f, 0.f, 0.f};

#define STAGE(NB, IT) do {                                                        \
        const char* asrc_ = (const char*)(wbase + (size_t)(IT) * 6144);           \
        _Pragma("unroll")                                                         \
        for (int i_ = 0; i_ < 6; ++i_)                                            \
            dma16(asrc_ + (i_ * 128 + tid) * 16,                                  \
                  (char*)(Ash[NB]) + (i_ * 128 + (w << 6)) * 16);                 \
        int k0_ = (IT) * 64;                                                      \
        _Pragma("unroll")                                                         \
        for (int i_ = 0; i_ < 2; ++i_)                                            \
            dma16(bg[i_] + k0_ * bstep[i_],                                       \
                  (char*)(Bsh[NB]) + (i_ * 128 + (w << 6)) * 16);                 \
    } while (0)

        // pipeline prologue: tile 0 into buffer 0, drain, barrier
        STAGE(0, 0);
        asm volatile("s_waitcnt vmcnt(0)" ::: "memory");
        __builtin_amdgcn_s_barrier();

#pragma unroll 2
        for (int it = 0; it < 16; ++it) {
            int cur = it & 1;
            if (it < 15) STAGE(cur ^ 1, it + 1);   // next tile in flight during compute

            const unsigned short* Acur = Ash[cur];
            const unsigned short* Bcur = Bsh[cur];
#pragma unroll
            for (int kt = 0; kt < 2; ++kt) {
                int kc = kt * 4 + l4;
                f16x8 bq[2];
#pragma unroll
                for (int q = 0; q < 2; ++q) {
                    if (q < nq) {
                        int s = q * 16 + l15;
                        int boff = s * 64 + ((kc ^ (s & 7)) * 8);
                        bq[q] = *(const f16x8*)(&Bcur[boff]);
                    }
                }
#pragma unroll
                for (int g = 0; g < 3; ++g) {
                    int r = g * 32 + w * 16 + l15;
                    int aoff = r * 64 + ((kc ^ (r & 7)) * 8);
                    f16x8 av = *(const f16x8*)(&Acur[aoff]);
#pragma unroll
                    for (int q = 0; q < 2; ++q) {
                        if (q < nq) {
                            acc[g][q] = __builtin_amdgcn_mfma_f32_16x16x32_f16(av, bq[q], acc[g][q], 0, 0, 0);
                        }
                    }
                }
            }
            if (it < 15) {
                asm volatile("s_waitcnt vmcnt(0)" ::: "memory");  // next tile landed
                __builtin_amdgcn_s_barrier();                     // all waves past reads of it-1 buf
            }
        }
#undef STAGE

        // ---- GRU epilogue (f32, coalesced stores only) ----
        int j = j0 + w * 16 + l4 * 4;
        f32x4 bhn = *(const f32x4*)(b_hh + c * G3 + 2 * HD + j);
#pragma unroll
        for (int q = 0; q < 2; ++q) {
            if (q < nq) {
                int b = slist[q * 16 + l15];
                if (b >= 0) {
                    const float* gib = gi + (size_t)b * G3;
                    f32x4 gr = *(const f32x4*)(gib + j);
                    f32x4 gz = *(const f32x4*)(gib + HD + j);
                    f32x4 gn = *(const f32x4*)(gib + 2 * HD + j);
                    f32x4 hp = *(const f32x4*)(h_in + (size_t)b * HD + j);
                    f32x4 hn;
#pragma unroll
                    for (int e = 0; e < 4; ++e) {
                        float r = sigf(gr[e] + acc[0][q][e]);
                        float z = sigf(gz[e] + acc[1][q][e]);
                        float n = tanhf(gn[e] + r * (acc[2][q][e] + bhn[e]));
                        hn[e] = (1.f - z) * n + z * hp[e];
                    }
                    unsigned int hw[2];
#pragma unroll
                    for (int e = 0; e < 2; ++e) {
                        unsigned short h0 = f2h(hn[2 * e]), h1 = f2h(hn[2 * e + 1]);
                        hw[e] = (unsigned)h0 | ((unsigned)h1 << 16);
                    }
                    *(f32x4*)(h_out + (size_t)b * HD + j) = hn;
                    *(uint2*)(hf_out + (size_t)b * HD + j) = make_uint2(hw[0], hw[1]);
                }
            }
        }
    }
}

// ---------------- ring [TCH][B][H] -> out [B][H][T] chunk transpose ----------------
__global__ __launch_bounds__(256) void tr_kernel(
    const float* __restrict__ ring, float* __restrict__ out, int t0) {
    int r = blockIdx.x * 256 + threadIdx.x;   // row in [0, B*H)
    float v[TCH];
#pragma unroll
    for (int tt = 0; tt < TCH; ++tt)
        v[tt] = ring[(size_t)tt * (BB * HD) + r];   // coalesced plane reads
    float* dst = out + (size_t)r * TT + t0;         // 80B contiguous per row
#pragma unroll
    for (int e = 0; e < TCH / 4; ++e)
        *(f32x4*)(dst + 4 * e) = (f32x4){v[4 * e], v[4 * e + 1], v[4 * e + 2], v[4 * e + 3]};
}

extern "C" void kernel_launch(void* const* d_in, const int* in_sizes, int n_in,
                              void* d_out, int out_size, void* d_ws, size_t ws_size,
                              hipStream_t stream) {
    const float* x    = (const float*)d_in[0];
    const int*   cam  = (const int*)d_in[1];
    const float* W_ih = (const float*)d_in[2];
    const float* W_hh = (const float*)d_in[3];
    const float* b_ih = (const float*)d_in[4];
    const float* b_hh = (const float*)d_in[5];
    float* out = (float*)d_out;

    char* ws = (char*)d_ws;
    int*   off   = (int*)ws;                               // 64 B
    int*   list  = (int*)(ws + 64);                        // 1 KB
    unsigned short* hzero = (unsigned short*)(ws + 2048);  // 2 KB zeros
    float* gi    = (float*)(ws + 4096);                    // 3 MB
    float* hZ    = (float*)(ws + 3149824);                 // 1 MB zero f32 plane (t=0 h_in)
    unsigned short* hfA = (unsigned short*)(ws + 4198400); // 512 KB fp16 h plane
    unsigned short* hfB = (unsigned short*)(ws + 4722688); // 512 KB fp16 h plane
    float* ring  = (float*)(ws + 5246976);                 // 20 MB: TCH x B x H f32
    unsigned short* Wimg = (unsigned short*)(ws + 26218496); // 94.4 MB fp16 image

    group_kernel<<<1, 256, 0, stream>>>(cam, off, list);
    gi_gemm_kernel<<<dim3(NCAM, G3 / 96), 256, 0, stream>>>(
        W_ih, b_ih, b_hh, x, off, list, gi);
    prep_kernel<<<dim3(48, 32, NCAM), 256, 0, stream>>>(W_hh, Wimg);
    hipMemsetAsync(hzero, 0, 2048, stream);
    hipMemsetAsync(hZ, 0, (size_t)BB * HD * sizeof(float), stream);
    hipMemsetAsync(hfA, 0, (size_t)BB * HD * sizeof(short), stream);

    const float* hin = hZ;
    const unsigned short* hf_in = hfA;
    unsigned short* hf_out = hfB;
    for (int t = 0; t < TT; ++t) {
        float* ringplane = ring + (size_t)(t % TCH) * BB * HD;
        step_dma_kernel<<<dim3(NCAM, HD / 32), 128, 0, stream>>>(
            Wimg, b_hh, gi, off, list, hin, hf_in, hzero,
            ringplane, hf_out);
        hin = ringplane;
        { const unsigned short* tmp = hf_in; hf_in = hf_out; hf_out = (unsigned short*)tmp; }
        if ((t % TCH) == TCH - 1)
            tr_kernel<<<BB * HD / 256, 256, 0, stream>>>(ring, out, t - (TCH - 1));
    }
}

// Round 4
// 1742.937 us; speedup vs baseline: 1.5481x; 1.0426x over previous
//
#include <hip/hip_runtime.h>
#include <math.h>

#define HD 1024
#define BB 256
#define NCAM 15
#define TT 60
#define G3 3072
#define LDW 36      // f32 LDS stride for gi kernel
#define NS 24       // samples per pass, gi kernel
#define TCH 20      // ring chunk (timesteps) for coalesced out staging

typedef _Float16 f16x8 __attribute__((ext_vector_type(8)));
typedef float f32x4 __attribute__((ext_vector_type(4)));

__device__ __forceinline__ unsigned short f2h(float f) {
    _Float16 h = (_Float16)f;             // v_cvt_f16_f32, RNE
    unsigned short u;
    __builtin_memcpy(&u, &h, 2);
    return u;
}
__device__ __forceinline__ float sigf(float v) { return 1.f / (1.f + expf(-v)); }

// async global->LDS, 16B per lane; LDS dest = wave-uniform base + lane*16
__device__ __forceinline__ void dma16(const void* g, void* l) {
    __builtin_amdgcn_global_load_lds(
        (const __attribute__((address_space(1))) unsigned int*)g,
        (__attribute__((address_space(3))) unsigned int*)l, 16, 0, 0);
}

// ---------------- grouping ----------------
__global__ void group_kernel(const int* __restrict__ cam,
                             int* __restrict__ off, int* __restrict__ list) {
    __shared__ int cnt[NCAM];
    __shared__ int soff[NCAM + 1];
    int tid = threadIdx.x;
    if (tid < NCAM) cnt[tid] = 0;
    __syncthreads();
    int c = cam[tid];
    int pos = atomicAdd(&cnt[c], 1);
    __syncthreads();
    if (tid == 0) {
        soff[0] = 0;
        for (int i = 0; i < NCAM; ++i) soff[i + 1] = soff[i] + cnt[i];
    }
    __syncthreads();
    list[soff[c] + pos] = tid;
    if (tid <= NCAM) off[tid] = soff[tid];
}

// ---------------- per-camera input projection (f32, unchanged) ----------------
__global__ __launch_bounds__(256) void gi_gemm_kernel(
    const float* __restrict__ W_ih, const float* __restrict__ b_ih,
    const float* __restrict__ b_hh, const float* __restrict__ x,
    const int* __restrict__ off, const int* __restrict__ list,
    float* __restrict__ gi) {
    int c  = blockIdx.x;
    int r0 = blockIdx.y * 96;
    int tid = threadIdx.x;
    int tx = tid & 7, ty = tid >> 3;

    __shared__ __align__(16) float wlds[96 * LDW];
    __shared__ __align__(16) float hlds[NS * LDW];
    __shared__ int slist[NS];

    int base = off[c];
    int nc = off[c + 1] - base;

    for (int s0 = 0; s0 < nc; s0 += NS) {
        __syncthreads();
        if (tid < NS) slist[tid] = (s0 + tid < nc) ? list[base + s0 + tid] : -1;
        __syncthreads();

        float acc[3][3];
#pragma unroll
        for (int g = 0; g < 3; ++g)
#pragma unroll
            for (int q = 0; q < 3; ++q) acc[g][q] = 0.f;

        for (int k0 = 0; k0 < HD; k0 += 32) {
#pragma unroll
            for (int i = 0; i < 3; ++i) {
                int idx = tid + 256 * i;
                int row = idx >> 3, col4 = idx & 7;
                float4 w = *(const float4*)(W_ih +
                    ((size_t)c * G3 + r0 + row) * HD + k0 + col4 * 4);
                *(float4*)(wlds + row * LDW + col4 * 4) = w;
            }
            {
                int s = tid >> 3, col4 = tid & 7;
                if (s < NS) {
                    int b = slist[s];
                    float4 hv = make_float4(0.f, 0.f, 0.f, 0.f);
                    if (b >= 0)
                        hv = *(const float4*)(x + (size_t)b * HD + k0 + col4 * 4);
                    *(float4*)(hlds + s * LDW + col4 * 4) = hv;
                }
            }
            __syncthreads();
#pragma unroll
            for (int kk = 0; kk < 32; kk += 4) {
                float4 w0 = *(const float4*)(wlds + (0 * 32 + ty) * LDW + kk);
                float4 w1 = *(const float4*)(wlds + (1 * 32 + ty) * LDW + kk);
                float4 w2 = *(const float4*)(wlds + (2 * 32 + ty) * LDW + kk);
#pragma unroll
                for (int q = 0; q < 3; ++q) {
                    float4 hv = *(const float4*)(hlds + (tx + 8 * q) * LDW + kk);
                    acc[0][q] += w0.x * hv.x + w0.y * hv.y + w0.z * hv.z + w0.w * hv.w;
                    acc[1][q] += w1.x * hv.x + w1.y * hv.y + w1.z * hv.z + w1.w * hv.w;
                    acc[2][q] += w2.x * hv.x + w2.y * hv.y + w2.z * hv.z + w2.w * hv.w;
                }
            }
            __syncthreads();
        }
#pragma unroll
        for (int q = 0; q < 3; ++q) {
            int b = slist[tx + 8 * q];
            if (b >= 0) {
#pragma unroll
                for (int g = 0; g < 3; ++g) {
                    int R = r0 + g * 32 + ty;
                    float bias = b_ih[c * G3 + R];
                    if (R < 2 * HD) bias += b_hh[c * G3 + R];
                    gi[(size_t)b * G3 + R] = acc[g][q] + bias;
                }
            }
        }
    }
}

// ---------------- W_hh -> fp16 DMA-image prep (single plane, unchanged) ----------------
__global__ __launch_bounds__(256) void prep_kernel(
    const float* __restrict__ W_hh, unsigned short* __restrict__ Wimg) {
    int c = blockIdx.z, jt = blockIdx.y;
    int lin = blockIdx.x * 256 + threadIdx.x;   // [0, 12288) = 16 iters * 768 chunks
    int it  = lin / 768;
    int rem = lin - it * 768;
    int r = rem >> 3, kcp = rem & 7;
    int gate = r >> 5, jl = r & 31;
    int kc = kcp ^ (r & 7);
    int k = it * 64 + kc * 8;
    const float* src = W_hh + ((size_t)c * G3 + gate * HD + jt * 32 + jl) * HD + k;
    float4 v0 = *(const float4*)src;
    float4 v1 = *(const float4*)(src + 4);
    float v[8] = {v0.x, v0.y, v0.z, v0.w, v1.x, v1.y, v1.z, v1.w};
    unsigned int hp[4];
#pragma unroll
    for (int e = 0; e < 4; ++e) {
        unsigned short h0 = f2h(v[2 * e]), h1 = f2h(v[2 * e + 1]);
        hp[e] = (unsigned)h0 | ((unsigned)h1 << 16);
    }
    unsigned short* dst = Wimg + ((size_t)(c * 32 + jt) * 16 + it) * 6144 + r * 64 + kcp * 8;
    *(uint4*)dst = make_uint4(hp[0], hp[1], hp[2], hp[3]);
}

// ---------------- fused recurrent step: 4-deep counted-vmcnt DMA pipeline ----------------
// Per K-iter: wait vmcnt(16) (stage it landed, 2 stages stay in flight), barrier,
// issue stage it+3, compute stage it. LDS exactly 64 KiB -> 2 blocks/CU.
__global__ __launch_bounds__(128) void step_dma_kernel(
    const unsigned short* __restrict__ Wimg, const float* __restrict__ b_hh,
    const float* __restrict__ gi, const int* __restrict__ off,
    const int* __restrict__ list, const float* __restrict__ h_in,
    const unsigned short* __restrict__ hf_in, const unsigned short* __restrict__ hzero,
    float* __restrict__ h_out, unsigned short* __restrict__ hf_out) {
    int c  = blockIdx.x;
    int jt = blockIdx.y;
    int j0 = jt * 32;
    int tid = threadIdx.x;
    int lane = tid & 63;
    int w = tid >> 6;
    int l15 = lane & 15;
    int l4  = lane >> 4;

    __shared__ __align__(16) unsigned short Ash[4][6144];  // 4 x (96 x 64 fp16) = 48 KB
    __shared__ __align__(16) unsigned short Bsh[4][2048];  // 4 x (32 x 64 fp16) = 16 KB

    const unsigned short* wbase = Wimg + (size_t)(c * 32 + jt) * 16 * 6144;
    int base = off[c];
    int nc = off[c + 1] - base;

    // B DMA decode (2 insts x 128 threads = 256 chunks = 32 s x 8 kc')
    int bs[2], bkc[2];
#pragma unroll
    for (int i = 0; i < 2; ++i) {
        int p = i * 128 + tid;
        bs[i]  = p >> 3;
        bkc[i] = (p & 7) ^ (bs[i] & 7);   // global k-chunk after inverse swizzle
    }

#define STG_A(NB, IT) do {                                                    \
        const char* asrc_ = (const char*)(wbase + (size_t)(IT) * 6144);       \
        _Pragma("unroll")                                                     \
        for (int i_ = 0; i_ < 6; ++i_)                                        \
            dma16(asrc_ + (i_ * 128 + tid) * 16,                              \
                  (char*)(Ash[NB]) + (i_ * 128 + (w << 6)) * 16);             \
    } while (0)
#define STG_B(NB, IT) do {                                                    \
        int k0_ = (IT) * 64;                                                  \
        _Pragma("unroll")                                                     \
        for (int i_ = 0; i_ < 2; ++i_)                                        \
            dma16(bg[i_] + k0_ * bstep[i_],                                   \
                  (char*)(Bsh[NB]) + (i_ * 128 + (w << 6)) * 16);             \
    } while (0)

    for (int s0 = 0; s0 < nc; s0 += 32) {
        __syncthreads();   // pass boundary: all waves done with previous buffers

        // slist in a register, broadcast via shfl (indices are < 32)
        int sv = -1;
        if (lane < 32) sv = (s0 + lane < nc) ? list[base + s0 + lane] : -1;

        int rem = nc - s0;
        int nq = (rem > 16) ? 2 : 1;

        const unsigned short* bg[2];
        int bstep[2];
#pragma unroll
        for (int i = 0; i < 2; ++i) {
            int b = __shfl(sv, bs[i]);
            bg[i] = (b >= 0) ? hf_in + (size_t)b * HD + bkc[i] * 8 : hzero;
            bstep[i] = (b >= 0) ? 1 : 0;
        }

        f32x4 acc[3][2];
#pragma unroll
        for (int g = 0; g < 3; ++g)
#pragma unroll
            for (int q = 0; q < 2; ++q) acc[g][q] = (f32x4){0.f, 0.f, 0.f, 0.f};

        // exact-count baseline: nothing outstanding before the prologue
        asm volatile("s_waitcnt vmcnt(0)" ::: "memory");

        // prologue: stages 0..2 in FIFO order [A0 B0 A1 B1 A2 B2] = 24 insts
        STG_A(0, 0); STG_B(0, 0);
        STG_A(1, 1); STG_B(1, 1);
        STG_A(2, 2); STG_B(2, 2);

#pragma unroll
        for (int it = 0; it < 16; ++it) {
            // counted wait: exactly stage it retired; 2 newer stages in flight
            if (it < 14)       asm volatile("s_waitcnt vmcnt(16)" ::: "memory");
            else if (it == 14) asm volatile("s_waitcnt vmcnt(8)"  ::: "memory");
            else               asm volatile("s_waitcnt vmcnt(0)"  ::: "memory");
            __builtin_amdgcn_s_barrier();
            if (it < 13) { STG_A((it + 3) & 3, it + 3); STG_B((it + 3) & 3, it + 3); }

            const unsigned short* Acur = Ash[it & 3];
            const unsigned short* Bcur = Bsh[it & 3];
#pragma unroll
            for (int kt = 0; kt < 2; ++kt) {
                int kc = kt * 4 + l4;
                f16x8 bq[2];
#pragma unroll
                for (int q = 0; q < 2; ++q) {
                    if (q < nq) {
                        int s = q * 16 + l15;
                        int boff = s * 64 + ((kc ^ (s & 7)) * 8);
                        bq[q] = *(const f16x8*)(&Bcur[boff]);
                    }
                }
#pragma unroll
                for (int g = 0; g < 3; ++g) {
                    int r = g * 32 + w * 16 + l15;
                    int aoff = r * 64 + ((kc ^ (r & 7)) * 8);
                    f16x8 av = *(const f16x8*)(&Acur[aoff]);
#pragma unroll
                    for (int q = 0; q < 2; ++q) {
                        if (q < nq) {
                            acc[g][q] = __builtin_amdgcn_mfma_f32_16x16x32_f16(av, bq[q], acc[g][q], 0, 0, 0);
                        }
                    }
                }
            }
        }

        // ---- GRU epilogue (f32, coalesced stores only) ----
        int j = j0 + w * 16 + l4 * 4;
        f32x4 bhn = *(const f32x4*)(b_hh + c * G3 + 2 * HD + j);
#pragma unroll
        for (int q = 0; q < 2; ++q) {
            if (q < nq) {
                int b = __shfl(sv, q * 16 + l15);
                if (b >= 0) {
                    const float* gib = gi + (size_t)b * G3;
                    f32x4 gr = *(const f32x4*)(gib + j);
                    f32x4 gz = *(const f32x4*)(gib + HD + j);
                    f32x4 gn = *(const f32x4*)(gib + 2 * HD + j);
                    f32x4 hp = *(const f32x4*)(h_in + (size_t)b * HD + j);
                    f32x4 hn;
#pragma unroll
                    for (int e = 0; e < 4; ++e) {
                        float r = sigf(gr[e] + acc[0][q][e]);
                        float z = sigf(gz[e] + acc[1][q][e]);
                        float n = tanhf(gn[e] + r * (acc[2][q][e] + bhn[e]));
                        hn[e] = (1.f - z) * n + z * hp[e];
                    }
                    unsigned int hw[2];
#pragma unroll
                    for (int e = 0; e < 2; ++e) {
                        unsigned short h0 = f2h(hn[2 * e]), h1 = f2h(hn[2 * e + 1]);
                        hw[e] = (unsigned)h0 | ((unsigned)h1 << 16);
                    }
                    *(f32x4*)(h_out + (size_t)b * HD + j) = hn;
                    *(uint2*)(hf_out + (size_t)b * HD + j) = make_uint2(hw[0], hw[1]);
                }
            }
        }
    }
#undef STG_A
#undef STG_B
}

// ---------------- ring [TCH][B][H] -> out [B][H][T] chunk transpose ----------------
__global__ __launch_bounds__(256) void tr_kernel(
    const float* __restrict__ ring, float* __restrict__ out, int t0) {
    int r = blockIdx.x * 256 + threadIdx.x;   // row in [0, B*H)
    float v[TCH];
#pragma unroll
    for (int tt = 0; tt < TCH; ++tt)
        v[tt] = ring[(size_t)tt * (BB * HD) + r];   // coalesced plane reads
    float* dst = out + (size_t)r * TT + t0;         // 80B contiguous per row
#pragma unroll
    for (int e = 0; e < TCH / 4; ++e)
        *(f32x4*)(dst + 4 * e) = (f32x4){v[4 * e], v[4 * e + 1], v[4 * e + 2], v[4 * e + 3]};
}

extern "C" void kernel_launch(void* const* d_in, const int* in_sizes, int n_in,
                              void* d_out, int out_size, void* d_ws, size_t ws_size,
                              hipStream_t stream) {
    const float* x    = (const float*)d_in[0];
    const int*   cam  = (const int*)d_in[1];
    const float* W_ih = (const float*)d_in[2];
    const float* W_hh = (const float*)d_in[3];
    const float* b_ih = (const float*)d_in[4];
    const float* b_hh = (const float*)d_in[5];
    float* out = (float*)d_out;

    char* ws = (char*)d_ws;
    int*   off   = (int*)ws;                               // 64 B
    int*   list  = (int*)(ws + 64);                        // 1 KB
    unsigned short* hzero = (unsigned short*)(ws + 2048);  // 2 KB zeros
    float* gi    = (float*)(ws + 4096);                    // 3 MB
    float* hZ    = (float*)(ws + 3149824);                 // 1 MB zero f32 plane (t=0 h_in)
    unsigned short* hfA = (unsigned short*)(ws + 4198400); // 512 KB fp16 h plane
    unsigned short* hfB = (unsigned short*)(ws + 4722688); // 512 KB fp16 h plane
    float* ring  = (float*)(ws + 5246976);                 // 20 MB: TCH x B x H f32
    unsigned short* Wimg = (unsigned short*)(ws + 26218496); // 94.4 MB fp16 image

    group_kernel<<<1, 256, 0, stream>>>(cam, off, list);
    gi_gemm_kernel<<<dim3(NCAM, G3 / 96), 256, 0, stream>>>(
        W_ih, b_ih, b_hh, x, off, list, gi);
    prep_kernel<<<dim3(48, 32, NCAM), 256, 0, stream>>>(W_hh, Wimg);
    hipMemsetAsync(hzero, 0, 2048, stream);
    hipMemsetAsync(hZ, 0, (size_t)BB * HD * sizeof(float), stream);
    hipMemsetAsync(hfA, 0, (size_t)BB * HD * sizeof(short), stream);

    const float* hin = hZ;
    const unsigned short* hf_in = hfA;
    unsigned short* hf_out = hfB;
    for (int t = 0; t < TT; ++t) {
        float* ringplane = ring + (size_t)(t % TCH) * BB * HD;
        step_dma_kernel<<<dim3(NCAM, HD / 32), 128, 0, stream>>>(
            Wimg, b_hh, gi, off, list, hin, hf_in, hzero,
            ringplane, hf_out);
        hin = ringplane;
        { const unsigned short* tmp = hf_in; hf_in = hf_out; hf_out = (unsigned short*)tmp; }
        if ((t % TCH) == TCH - 1)
            tr_kernel<<<BB * HD / 256, 256, 0, stream>>>(ring, out, t - (TCH - 1));
    }
}